// Round 2
// baseline (115.858 us; speedup 1.0000x reference)
//
#include <hip/hip_runtime.h>

#define NROIS 128
#define OUTD  12
#define NVOX  (OUTD * OUTD * OUTD)
#define NCH   64
#define NKEYS (NROIS * NVOX)          // 221184 (roi,voxel) keys
#define QCAP  2048                    // LDS hit-queue capacity (mean ~28/block)
#define OVF   2048                    // per-block ws overflow slots (never in practice)
#define STAMP 0x5AFE5AFEu             // != 0, != 0xAAAAAAAA harness poison
#define CELLS 18                      // 18x18 xy grid, 5 m cells over [-45,45]^2
#define NCELL (CELLS * CELLS)
#define CSLOT 32                      // roi slots per cell (avg ~4, max ~12)

// Order-preserving encode of float32 into uint32 for atomicMax.
// f >= 0 -> bits | 0x80000000 ; f < 0 -> ~bits. Encoded real floats are never 0,
// so 0u marks "empty" (and decodes to +0.0f).
__device__ __forceinline__ unsigned enc_f32(float f) {
    unsigned b = __float_as_uint(f);
    return (b & 0x80000000u) ? ~b : (b | 0x80000000u);
}

__device__ __forceinline__ float dec_key(unsigned k) {
    unsigned b = (k & 0x80000000u) ? (k & 0x7fffffffu) : ~k;
    return __uint_as_float(b);
}

// Kernel A: grid-stride uint4 zero of out (BW-bound, ~9us) fused with ROI
// param precompute + spatial-hash build (block 0 only, overlapped with fill).
// Cell cover uses the circumscribed reject circle with monotone float math:
// for any point passing the exact test, |px-cx| < sqrt(R2m) <= rb, and
// fl((px+45)*0.2) is monotone in px, so the point's cell is inside the roi's
// cell rect -> provable superset. Cell-slot overflow -> scatter falls back to
// scanning all 128 rois for that cell (correct, never triggers).
__global__ void __launch_bounds__(256) fill_prep(
        const float* __restrict__ rois,   // (128, 7)
        unsigned*    __restrict__ out,    // (128*1728*64) u32
        float4*      __restrict__ prej,   // [128] cx, cy, zc, zh
        float*       __restrict__ prad,   // [128] conservative radius^2
        float4*      __restrict__ pfull,  // [384] exact params
        int*         __restrict__ ccnt,   // [324] rois per cell
        unsigned char* __restrict__ ctab) // [324*32] roi ids
{
    const int tid = threadIdx.x;
    if (blockIdx.x == 0) {
        __shared__ int           lcnt[NCELL];
        __shared__ unsigned char ltab[NCELL * CSLOT];
        for (int i = tid; i < NCELL; i += 256) lcnt[i] = 0;
        __syncthreads();
        if (tid < NROIS) {
            int r = tid;
            // Exact reference-sequence params (bit-identical to the reference).
            float cx = rois[7 * r + 0];
            float cy = rois[7 * r + 1];
            float cz = rois[7 * r + 2];
            float dx = rois[7 * r + 3];
            float dy = rois[7 * r + 4];
            float dz = rois[7 * r + 5];
            float nrz = -rois[7 * r + 6];
            float ca = cosf(nrz), sa = sinf(nrz);
            float hx = __fmul_rn(dx, 0.5f);
            float hy = __fmul_rn(dy, 0.5f);
            float hz = __fmul_rn(dz, 0.5f);
            pfull[3 * r + 0] = make_float4(cx, cy, cz, ca);
            pfull[3 * r + 1] = make_float4(sa, hx, hy, hz);
            pfull[3 * r + 2] = make_float4(__fdiv_rn(dx, 12.0f),
                                           __fdiv_rn(dy, 12.0f),
                                           __fdiv_rn(dz, 12.0f), 0.0f);
            // Conservative superset reject (circle + z window).
            float R2  = 0.25f * (dx * dx + dy * dy);
            float R2m = R2 * 1.04f + 1e-4f;
            prad[r] = R2m;
            prej[r] = make_float4(cx, cy, cz + hz, hz * 1.001f + 1e-3f);
            // Cell cover rect (rb strictly dominates sqrt(R2m)).
            float rb = sqrtf(R2m) * 1.001f + 0.02f;
            int x0 = min(max((int)floorf((cx - rb + 45.0f) * 0.2f), 0), CELLS - 1);
            int x1 = min(max((int)floorf((cx + rb + 45.0f) * 0.2f), 0), CELLS - 1);
            int y0 = min(max((int)floorf((cy - rb + 45.0f) * 0.2f), 0), CELLS - 1);
            int y1 = min(max((int)floorf((cy + rb + 45.0f) * 0.2f), 0), CELLS - 1);
            for (int xx = x0; xx <= x1; ++xx)
                for (int yy = y0; yy <= y1; ++yy) {
                    int c = xx * CELLS + yy;
                    int s = atomicAdd(&lcnt[c], 1);
                    if (s < CSLOT) ltab[c * CSLOT + s] = (unsigned char)r;
                }
        }
        __syncthreads();
        for (int i = tid; i < NCELL; i += 256) ccnt[i] = lcnt[i];
        for (int i = tid; i < NCELL * CSLOT; i += 256) ctab[i] = ltab[i];
    }
    // Zero the accumulator (0u == empty == 0.0f bits).
    uint4* o16 = (uint4*)out;
    const int tot16 = NKEYS * (NCH / 4);              // 3,538,944 uint4
    const uint4 z = make_uint4(0u, 0u, 0u, 0u);
    for (int i = blockIdx.x * 256 + tid; i < tot16; i += gridDim.x * 256)
        o16[i] = z;
}

// Kernel B: one pass over points (read once). Per point: hash to cell, test
// only that cell's ~4 rois (conservative reject -> exact reference test).
// Hits queued in LDS, drained wave-cooperatively (lane = channel): one
// coalesced 256B feat load + one coalesced 256B atomicMax per hit, plus an
// idempotent stamp store marking the voxel touched for the decode pass.
__global__ void __launch_bounds__(256) roi_pool_scatter(
        const float* __restrict__ pts,      // (P, 3)
        const float* __restrict__ feat,     // (P, 64)
        unsigned*    __restrict__ out,      // (128, 1728, 64) encoded keys
        unsigned*    __restrict__ stamp,    // u32[NKEYS] touched markers
        const float4* __restrict__ prej,
        const float*  __restrict__ prad,
        const float4* __restrict__ pfull,
        const int*    __restrict__ ccnt,
        const unsigned char* __restrict__ ctab,
        unsigned long long*  __restrict__ ovf,
        int npts)
{
    __shared__ unsigned sQp[QCAP];
    __shared__ unsigned sQk[QCAP];
    __shared__ unsigned sQn;

    const int tid = threadIdx.x;
    if (tid == 0) sQn = 0;
    __syncthreads();

    int p = blockIdx.x * 256 + tid;
    if (p < npts) {
        float px = pts[3 * p + 0];
        float py = pts[3 * p + 1];
        float pz = pts[3 * p + 2];

        int cxi  = min(max((int)floorf((px + 45.0f) * 0.2f), 0), CELLS - 1);
        int cyi  = min(max((int)floorf((py + 45.0f) * 0.2f), 0), CELLS - 1);
        int cell = cxi * CELLS + cyi;
        int n    = ccnt[cell];
        bool fallback = (n > CSLOT);      // slot overflow: scan everything
        int  m = fallback ? NROIS : n;

        for (int i = 0; i < m; ++i) {
            int r = fallback ? i : (int)ctab[cell * CSLOT + i];
            // conservative reject (circle + z window); margins dwarf fp noise
            float4 q = prej[r];
            float sx0 = px - q.x;
            float sy0 = py - q.y;
            float d2 = sx0 * sx0 + sy0 * sy0;   // contraction ok: margin absorbs
            if (!((d2 < prad[r]) & (fabsf(pz - q.z) <= q.w))) continue;

            // exact reference test (bit-identical float sequence)
            float4 F0 = pfull[3 * r + 0];
            float4 F1 = pfull[3 * r + 1];
            float sx = __fsub_rn(px, F0.x);
            float sy = __fsub_rn(py, F0.y);
            float sz = __fsub_rn(pz, F0.z);
            float ca = F0.w, sa = F1.x;
            float hx = F1.y, hy = F1.z, hz = F1.w;
            float lx = __fsub_rn(__fmul_rn(sx, ca), __fmul_rn(sy, sa));
            float ly = __fadd_rn(__fmul_rn(sx, sa), __fmul_rn(sy, ca));

            bool in_box = (lx > -hx) && (lx < hx) &&
                          (ly > -hy) && (ly < hy) &&
                          (fabsf(__fsub_rn(sz, hz)) <= hz);
            if (!in_box) continue;

            float4 F2 = pfull[3 * r + 2];
            int xi = (int)floorf(__fdiv_rn(__fadd_rn(lx, hx), F2.x));
            int yi = (int)floorf(__fdiv_rn(__fadd_rn(ly, hy), F2.y));
            int zi = (int)floorf(__fdiv_rn(sz,                F2.z));
            xi = min(max(xi, 0), OUTD - 1);
            yi = min(max(yi, 0), OUTD - 1);
            zi = min(max(zi, 0), OUTD - 1);

            unsigned key = (unsigned)(r * NVOX +
                                      xi * (OUTD * OUTD) + yi * OUTD + zi);

            unsigned idx = atomicAdd(&sQn, 1u);
            if (idx < QCAP) {
                sQp[idx] = (unsigned)p;
                sQk[idx] = key;
            } else if (idx - QCAP < OVF) {
                ovf[(size_t)blockIdx.x * OVF + (idx - QCAP)] =
                    ((unsigned long long)key << 32) | (unsigned)p;
            }
        }
    }

    __syncthreads();
    // Wave-cooperative drain: one queue entry per wave, lane = channel.
    int nq   = min((int)sQn, QCAP + OVF);
    int wid  = tid >> 6;
    int lane = tid & 63;
    for (int i = wid; i < nq; i += 4) {
        unsigned pp, kk;
        if (i < QCAP) {
            pp = sQp[i];
            kk = sQk[i];
        } else {
            unsigned long long e = ovf[(size_t)blockIdx.x * OVF + (i - QCAP)];
            pp = (unsigned)e;
            kk = (unsigned)(e >> 32);
        }
        if (lane == 0) stamp[kk] = STAMP;   // idempotent, fire-and-forget
        float f = feat[(size_t)pp * NCH + lane];
        atomicMax(out + (size_t)kk * NCH + lane, enc_f32(f));
    }
}

// Kernel C: sparse decode. One wave per 64 keys; ballot gives the touched
// set; each touched key's 64 channels decoded with lane = channel. Untouched
// voxels keep the zero fill (0u == 0.0f). Stale STAMPs (if ws not re-poisoned
// between replays) are benign: their channels read 0u -> write 0u.
__global__ void __launch_bounds__(256) decode_touched(
        unsigned* __restrict__ out,
        const unsigned* __restrict__ stamp)
{
    int w    = (blockIdx.x * blockDim.x + threadIdx.x) >> 6;
    int lane = threadIdx.x & 63;
    int base = w * 64;
    if (base >= NKEYS) return;
    unsigned s = stamp[base + lane];
    unsigned long long m = __ballot(s == STAMP);
    while (m) {
        int b = __ffsll((long long)m) - 1;
        m &= m - 1;
        unsigned key = (unsigned)(base + b);
        unsigned* v = out + (size_t)key * NCH;
        unsigned k = v[lane];
        v[lane] = (k == 0u) ? 0u : __float_as_uint(dec_key(k));
    }
}

extern "C" void kernel_launch(void* const* d_in, const int* in_sizes, int n_in,
                              void* d_out, int out_size, void* d_ws, size_t ws_size,
                              hipStream_t stream)
{
    const float* rois = (const float*)d_in[0];
    const float* pts  = (const float*)d_in[1];
    const float* feat = (const float*)d_in[2];
    int npts = in_sizes[1] / 3;

    // ws layout (all rebuilt every iteration; stale stamp is benign):
    //   [0]        stamp   u32[NKEYS]           884 KB
    //   [1 MB]     prej    float4[128]            2 KB
    //   [1MB+2K]   prad    float[128]           0.5 KB
    //   [1MB+4K]   pfull   float4[384]            6 KB
    //   [1MB+12K]  ccnt    int[324]             1.3 KB
    //   [1MB+16K]  ctab    u8[324*32]          10.1 KB
    //   [2 MB]     ovf     u64[625*2048]       10.2 MB
    char* ws = (char*)d_ws;
    unsigned*           stamp = (unsigned*)ws;
    float4*             prej  = (float4*)(ws + (1 << 20));
    float*              prad  = (float*) (ws + (1 << 20) + 2048);
    float4*             pfull = (float4*)(ws + (1 << 20) + 4096);
    int*                ccnt  = (int*)   (ws + (1 << 20) + 12288);
    unsigned char*      ctab  = (unsigned char*)(ws + (1 << 20) + 16384);
    unsigned long long* ovf   = (unsigned long long*)(ws + (2 << 20));
    unsigned*           out   = (unsigned*)d_out;

    fill_prep<<<2048, 256, 0, stream>>>(rois, out, prej, prad, pfull, ccnt, ctab);

    int nblk = (npts + 255) / 256;          // 625
    roi_pool_scatter<<<nblk, 256, 0, stream>>>(pts, feat, out, stamp,
                                               prej, prad, pfull, ccnt, ctab,
                                               ovf, npts);

    decode_touched<<<NKEYS / 256, 256, 0, stream>>>(out, stamp);
}